// Round 13
// baseline (124.923 us; speedup 1.0000x reference)
//
#include <hip/hip_runtime.h>
#include <math.h>

#define BB 2
#define TT 512
#define UU 48
#define DD 512
#define HH 1024
#define KK 128

typedef _Float16 f16x8 __attribute__((ext_vector_type(8)));
typedef __fp16 fp16x2_t __attribute__((ext_vector_type(2)));
typedef float floatx4 __attribute__((ext_vector_type(4)));

// tanh from pre-scaled input z = 2*log2(e)*x (stored f16 by mid):
// tanh(x) = 1 - 2/(2^z + 1). 2 trans + ~5 VALU per 2 elems, +-inf safe.
__device__ __forceinline__ f16x8 tanh8z(f16x8 z) {
    f16x8 o;
#pragma unroll
    for (int i = 0; i < 8; i += 2) {
        float e0 = __builtin_amdgcn_exp2f((float)z[i]);
        float e1 = __builtin_amdgcn_exp2f((float)z[i + 1]);
        float r0 = __builtin_amdgcn_rcpf(e0 + 1.0f);
        float r1 = __builtin_amdgcn_rcpf(e1 + 1.0f);
        fp16x2_t p = __builtin_amdgcn_cvt_pkrtz(fmaf(-2.0f, r0, 1.0f),
                                                fmaf(-2.0f, r1, 1.0f));
        o[i] = (_Float16)p[0];
        o[i + 1] = (_Float16)p[1];
    }
    return o;
}

// ---------------- mid v5: unchanged --------------------------------------
__global__ __launch_bounds__(256) void mid_kernel5(
    const float* __restrict__ img, const float* __restrict__ labf,
    const float* __restrict__ W1, const float* __restrict__ W2,
    const float* __restrict__ conv_w,
    const float* __restrict__ b1, const float* __restrict__ conv_b,
    const float* __restrict__ masks,
    _Float16* __restrict__ imgHf, _Float16* __restrict__ labHf,
    _Float16* __restrict__ W2s, float* __restrict__ seg_out) {
    int bid = blockIdx.x, tid = threadIdx.x;
    if (bid >= 624) {  // W2 swizzle: W2s[(h>>3)*1024 + k*8 + (h&7)] = W2[k][h]
        int base = (bid - 624) * 256 + tid;
#pragma unroll
        for (int i = 0; i < 32; ++i) {
            int o = base + i * 4096;
            int hg = o >> 10, kk2 = (o >> 3) & 127, hl = o & 7;
            W2s[o] = (_Float16)W2[(size_t)kk2 * HH + hg * 8 + hl];
        }
        return;
    }
    __shared__ __align__(16) _Float16 a_s[32][72];
    __shared__ __align__(16) _Float16 w_s[4096];  // [8 kgroups][64 n][8]
    const float* Arow;
    const float* Wbase;
    int r0, n0b, wstride, region;
    if (bid < 512) {
        region = 0; Arow = img; Wbase = W1 + 512; wstride = 2 * DD;
        int xcd = bid & 7, j = bid >> 3;
        r0 = (j & 31) * 32; n0b = (xcd * 2 + (j >> 5)) * 64;
    } else if (bid < 560) {
        region = 1; Arow = labf; Wbase = W1; wstride = 2 * DD;
        int i = bid - 512; r0 = (i % 3) * 32; n0b = (i / 3) * 64;
    } else {
        region = 2; Arow = img; Wbase = conv_w; wstride = DD;
        int i = bid - 560; r0 = (i >> 1) * 32; n0b = (i & 1) * 64;
    }
    int lane = tid & 63, wv = tid >> 6;
    int m0 = (wv & 1) * 16, n0w = (wv >> 1) * 32;
    int q = lane >> 4, r = lane & 15;
    int arow = tid >> 3, acol = (tid & 7) * 8;
    int wn = tid >> 2, wk0 = (tid & 3) * 16;  // 4 threads per W row, 16 k each
    const float* aptr = &Arow[(size_t)(r0 + arow) * DD + acol];
    const float* wptr = &Wbase[(size_t)(n0b + wn) * wstride + wk0];
    floatx4 acc[2] = {};
    float4 pa0, pa1, pw[4];
    pa0 = *(const float4*)aptr;
    pa1 = *(const float4*)(aptr + 4);
#pragma unroll
    for (int i2 = 0; i2 < 4; ++i2) pw[i2] = *(const float4*)(wptr + i2 * 4);
    for (int c = 0; c < 8; ++c) {
        f16x8 av;
        av[0] = (_Float16)pa0.x; av[1] = (_Float16)pa0.y;
        av[2] = (_Float16)pa0.z; av[3] = (_Float16)pa0.w;
        av[4] = (_Float16)pa1.x; av[5] = (_Float16)pa1.y;
        av[6] = (_Float16)pa1.z; av[7] = (_Float16)pa1.w;
        *(f16x8*)&a_s[arow][acol] = av;
        f16x8 w0, w1;
        w0[0] = (_Float16)pw[0].x; w0[1] = (_Float16)pw[0].y;
        w0[2] = (_Float16)pw[0].z; w0[3] = (_Float16)pw[0].w;
        w0[4] = (_Float16)pw[1].x; w0[5] = (_Float16)pw[1].y;
        w0[6] = (_Float16)pw[1].z; w0[7] = (_Float16)pw[1].w;
        w1[0] = (_Float16)pw[2].x; w1[1] = (_Float16)pw[2].y;
        w1[2] = (_Float16)pw[2].z; w1[3] = (_Float16)pw[2].w;
        w1[4] = (_Float16)pw[3].x; w1[5] = (_Float16)pw[3].y;
        w1[6] = (_Float16)pw[3].z; w1[7] = (_Float16)pw[3].w;
        int kg = wk0 >> 3;
        *(f16x8*)&w_s[((kg + 0) * 64 + wn) * 8] = w0;
        *(f16x8*)&w_s[((kg + 1) * 64 + wn) * 8] = w1;
        __syncthreads();
        if (c < 7) {
            int cb = (c + 1) * 64;
            pa0 = *(const float4*)(aptr + cb);
            pa1 = *(const float4*)(aptr + cb + 4);
#pragma unroll
            for (int i2 = 0; i2 < 4; ++i2)
                pw[i2] = *(const float4*)(wptr + cb + i2 * 4);
        }
#pragma unroll
        for (int kt = 0; kt < 2; ++kt) {
            f16x8 af = *(const f16x8*)&a_s[m0 + r][kt * 32 + q * 8];
#pragma unroll
            for (int nt = 0; nt < 2; ++nt) {
                f16x8 bf = *(const f16x8*)
                    &w_s[((kt * 4 + q) * 64 + n0w + nt * 16 + r) * 8];
                acc[nt] = __builtin_amdgcn_mfma_f32_16x16x32_f16(
                    af, bf, acc[nt], 0, 0, 0);
            }
        }
        __syncthreads();
    }
    const float SC = 2.8853900817779268f;  // 2*log2(e): pre-scale for tanh8z
    if (region == 0) {
#pragma unroll
        for (int nt = 0; nt < 2; ++nt) {
            int n = n0b + n0w + nt * 16 + r;
#pragma unroll
            for (int rr = 0; rr < 4; ++rr)
                imgHf[(size_t)(r0 + m0 + 4 * q + rr) * HH + n] =
                    (_Float16)(acc[nt][rr] * SC);
        }
    } else if (region == 1) {
#pragma unroll
        for (int nt = 0; nt < 2; ++nt) {
            int n = n0b + n0w + nt * 16 + r;
            float bv = b1[n];
#pragma unroll
            for (int rr = 0; rr < 4; ++rr)
                labHf[(size_t)(r0 + m0 + 4 * q + rr) * HH + n] =
                    (_Float16)((acc[nt][rr] + bv) * SC);
        }
    } else {
#pragma unroll
        for (int nt = 0; nt < 2; ++nt) {
            int k = n0b + n0w + nt * 16 + r;
            float bv = conv_b[k];
#pragma unroll
            for (int rr = 0; rr < 4; ++rr) {
                int row = r0 + m0 + 4 * q + rr;
                int b = row >> 9, t = row & 511;
                seg_out[((size_t)b * KK + k) * TT + t] =
                    (acc[nt][rr] + bv) * masks[row];
            }
        }
    }
}

// ---------------- joint v17: v16 + B-frag m-sharing (2 m-tiles/wave) -------
// v16 is LDS-BW-bound; dominant term = bf reads (each wave reads the full
// 16KB W2 chunk for only 16 rows). v17: wave = 32 rows (2 m-tiles), each bf
// feeds 2 MFMAs -> per-CU LDS traffic 312KB -> 204KB per chunk. 768 blocks
// x 128 thr (2 waves), block = 64 rows x 128 cols, 3 blocks/CU. Schedule,
// staging style, softmax all byte-identical to v16 (mid pattern): reg-staged
// coalesced loads -> LDS, 2 barriers/chunk, single buffer, rolled loop.
__global__ __launch_bounds__(128) void joint_kernel17(
    const _Float16* __restrict__ imgHf,  // [B*T][H], pre-scaled 2log2e
    const _Float16* __restrict__ labHf,  // [B*U][H], (.+b1) pre-scaled
    const _Float16* __restrict__ W2s,    // swizzled [(h>>3)][k][h&7]
    const float* __restrict__ b2,
    float* __restrict__ out) {           // [B*U*T][K]
    __shared__ __align__(16) _Float16 a_s[64][72];  // 9 KB (+8 pad per row)
    __shared__ __align__(16) _Float16 w_s[8192];    // 16 KB: [8 hg][128 k][8]
    __shared__ __align__(16) _Float16 l_s[64];      // lab chunk (128 B)
    int tid = threadIdx.x, bid = blockIdx.x;
    int lane = tid & 63, wm = tid >> 6;  // 2 waves x 32 rows
    int ql = lane >> 4, r = lane & 15;
    int g0 = bid * 64;               // block's first flat (b,u,t) row
    int bu = g0 >> 9;                // single u per block (64 | 512)
    int tbase = ((bu >= UU) ? TT : 0) + (g0 & 511);
    // coalesced stage mappings: A: 2 thr/row x 64B; W2: 8 x 16B per thread
    int arow = tid >> 1, acol = (tid & 1) * 32;
    const _Float16* ap = imgHf + (size_t)(tbase + arow) * HH + acol;
    const _Float16* wq = W2s + (size_t)tid * 8;
    const _Float16* lp = labHf + (size_t)bu * HH;
    int m0 = wm * 32;                // wave's row base within block
    floatx4 acc0[8] = {}, acc1[8] = {};
    f16x8 pa[4], pw[8], plab;
    // prologue: chunk 0 -> regs
#pragma unroll
    for (int j = 0; j < 4; ++j) pa[j] = *(const f16x8*)(ap + j * 8);
#pragma unroll
    for (int j = 0; j < 8; ++j) pw[j] = *(const f16x8*)(wq + j * 1024);
    if (tid < 8) plab = *(const f16x8*)(lp + tid * 8);
#pragma unroll 1
    for (int c = 0; c < 16; ++c) {
        // store staged regs -> LDS
#pragma unroll
        for (int j = 0; j < 4; ++j) *(f16x8*)&a_s[arow][acol + j * 8] = pa[j];
#pragma unroll
        for (int j = 0; j < 8; ++j) *(f16x8*)&w_s[tid * 8 + j * 1024] = pw[j];
        if (tid < 8) *(f16x8*)&l_s[tid * 8] = plab;
        __syncthreads();
        // issue next chunk's loads; they drain during tanh+MFMA below
        if (c < 15) {
            int cb = (c + 1) * 64;
#pragma unroll
            for (int j = 0; j < 4; ++j)
                pa[j] = *(const f16x8*)(ap + cb + j * 8);
            const _Float16* wc = wq + (size_t)(c + 1) * 8192;
#pragma unroll
            for (int j = 0; j < 8; ++j) pw[j] = *(const f16x8*)(wc + j * 1024);
            if (tid < 8) plab = *(const f16x8*)(lp + cb + tid * 8);
        }
        // compute: 2 k-steps; each bf feeds BOTH m-tiles
#pragma unroll
        for (int kt = 0; kt < 2; ++kt) {
            f16x8 lf = *(const f16x8*)&l_s[kt * 32 + ql * 8];
            f16x8 af0 = *(const f16x8*)&a_s[m0 + r][kt * 32 + ql * 8];
            f16x8 af1 = *(const f16x8*)&a_s[m0 + 16 + r][kt * 32 + ql * 8];
            f16x8 a0 = tanh8z(af0 + lf);
            f16x8 a1 = tanh8z(af1 + lf);
#pragma unroll
            for (int nt = 0; nt < 8; ++nt) {
                f16x8 bf = *(const f16x8*)
                    &w_s[((kt * 4 + ql) * 128 + nt * 16 + r) * 8];
                acc0[nt] = __builtin_amdgcn_mfma_f32_16x16x32_f16(
                    a0, bf, acc0[nt], 0, 0, 0);
                acc1[nt] = __builtin_amdgcn_mfma_f32_16x16x32_f16(
                    a1, bf, acc1[nt], 0, 0, 0);
            }
        }
        __syncthreads();
    }
    // epilogue: +b2, in-register log-softmax (wave owns full 128 cols)
    float b2v[8];
#pragma unroll
    for (int nt = 0; nt < 8; ++nt) b2v[nt] = b2[nt * 16 + r];
#pragma unroll
    for (int mt = 0; mt < 2; ++mt) {
#pragma unroll
        for (int rr = 0; rr < 4; ++rr) {
            float v[8];
            float mx = -INFINITY;
#pragma unroll
            for (int nt = 0; nt < 8; ++nt) {
                v[nt] = (mt ? acc1[nt][rr] : acc0[nt][rr]) + b2v[nt];
                mx = fmaxf(mx, v[nt]);
            }
            mx = fmaxf(mx, __shfl_xor(mx, 1, 16));
            mx = fmaxf(mx, __shfl_xor(mx, 2, 16));
            mx = fmaxf(mx, __shfl_xor(mx, 4, 16));
            mx = fmaxf(mx, __shfl_xor(mx, 8, 16));
            float s = 0.f;
#pragma unroll
            for (int nt = 0; nt < 8; ++nt) s += __expf(v[nt] - mx);
            s += __shfl_xor(s, 1, 16);
            s += __shfl_xor(s, 2, 16);
            s += __shfl_xor(s, 4, 16);
            s += __shfl_xor(s, 8, 16);
            float lse = mx + __logf(s);
            float* orow =
                out + (size_t)(g0 + m0 + mt * 16 + 4 * ql + rr) * KK;
#pragma unroll
            for (int nt = 0; nt < 8; ++nt)
                orow[nt * 16 + r] = v[nt] - lse;
        }
    }
}

extern "C" void kernel_launch(void* const* d_in, const int* in_sizes, int n_in,
                              void* d_out, int out_size, void* d_ws, size_t ws_size,
                              hipStream_t stream) {
    const float* img    = (const float*)d_in[0];
    const float* labf   = (const float*)d_in[1];
    const float* masks  = (const float*)d_in[2];
    const float* W1     = (const float*)d_in[3];
    const float* b1     = (const float*)d_in[4];
    const float* W2     = (const float*)d_in[5];
    const float* b2     = (const float*)d_in[6];
    const float* conv_w = (const float*)d_in[7];
    const float* conv_b = (const float*)d_in[8];
    float* out = (float*)d_out;

    _Float16* base  = (_Float16*)d_ws;
    _Float16* imgHf = base;                    // [1024][1024]
    _Float16* labHf = imgHf + 1024 * 1024;     // [96][1024]
    _Float16* W2s   = labHf + 96 * 1024;       // [H/8][K][8] = 131072

    mid_kernel5<<<640, 256, 0, stream>>>(img, labf, W1, W2, conv_w,
                                         b1, conv_b, masks,
                                         imgHf, labHf, W2s, out);
    joint_kernel17<<<768, 128, 0, stream>>>(imgHf, labHf, W2s, b2,
                                            out + (size_t)BB * KK * TT);
}

// Round 14
// 122.979 us; speedup vs baseline: 1.0158x; 1.0158x over previous
//
#include <hip/hip_runtime.h>
#include <math.h>

#define BB 2
#define TT 512
#define UU 48
#define DD 512
#define HH 1024
#define KK 128

typedef _Float16 f16x8 __attribute__((ext_vector_type(8)));
typedef __fp16 fp16x2_t __attribute__((ext_vector_type(2)));
typedef float floatx4 __attribute__((ext_vector_type(4)));
typedef __attribute__((address_space(3))) _Float16 lds_f16;
typedef __attribute__((address_space(1))) const void g_cvoid;
typedef __attribute__((address_space(3))) void l_void;

// tanh from pre-scaled input z = 2*log2(e)*x (stored f16 by mid):
// tanh(x) = 1 - 2/(2^z + 1). 2 trans + ~5 VALU per 2 elems, +-inf safe.
__device__ __forceinline__ f16x8 tanh8z(f16x8 z) {
    f16x8 o;
#pragma unroll
    for (int i = 0; i < 8; i += 2) {
        float e0 = __builtin_amdgcn_exp2f((float)z[i]);
        float e1 = __builtin_amdgcn_exp2f((float)z[i + 1]);
        float r0 = __builtin_amdgcn_rcpf(e0 + 1.0f);
        float r1 = __builtin_amdgcn_rcpf(e1 + 1.0f);
        fp16x2_t p = __builtin_amdgcn_cvt_pkrtz(fmaf(-2.0f, r0, 1.0f),
                                                fmaf(-2.0f, r1, 1.0f));
        o[i] = (_Float16)p[0];
        o[i + 1] = (_Float16)p[1];
    }
    return o;
}

// ---------------- mid v5: unchanged --------------------------------------
__global__ __launch_bounds__(256) void mid_kernel5(
    const float* __restrict__ img, const float* __restrict__ labf,
    const float* __restrict__ W1, const float* __restrict__ W2,
    const float* __restrict__ conv_w,
    const float* __restrict__ b1, const float* __restrict__ conv_b,
    const float* __restrict__ masks,
    _Float16* __restrict__ imgHf, _Float16* __restrict__ labHf,
    _Float16* __restrict__ W2s, float* __restrict__ seg_out) {
    int bid = blockIdx.x, tid = threadIdx.x;
    if (bid >= 624) {  // W2 swizzle: W2s[(h>>3)*1024 + k*8 + (h&7)] = W2[k][h]
        int base = (bid - 624) * 256 + tid;
#pragma unroll
        for (int i = 0; i < 32; ++i) {
            int o = base + i * 4096;
            int hg = o >> 10, kk2 = (o >> 3) & 127, hl = o & 7;
            W2s[o] = (_Float16)W2[(size_t)kk2 * HH + hg * 8 + hl];
        }
        return;
    }
    __shared__ __align__(16) _Float16 a_s[32][72];
    __shared__ __align__(16) _Float16 w_s[4096];  // [8 kgroups][64 n][8]
    const float* Arow;
    const float* Wbase;
    int r0, n0b, wstride, region;
    if (bid < 512) {
        region = 0; Arow = img; Wbase = W1 + 512; wstride = 2 * DD;
        int xcd = bid & 7, j = bid >> 3;
        r0 = (j & 31) * 32; n0b = (xcd * 2 + (j >> 5)) * 64;
    } else if (bid < 560) {
        region = 1; Arow = labf; Wbase = W1; wstride = 2 * DD;
        int i = bid - 512; r0 = (i % 3) * 32; n0b = (i / 3) * 64;
    } else {
        region = 2; Arow = img; Wbase = conv_w; wstride = DD;
        int i = bid - 560; r0 = (i >> 1) * 32; n0b = (i & 1) * 64;
    }
    int lane = tid & 63, wv = tid >> 6;
    int m0 = (wv & 1) * 16, n0w = (wv >> 1) * 32;
    int q = lane >> 4, r = lane & 15;
    int arow = tid >> 3, acol = (tid & 7) * 8;
    int wn = tid >> 2, wk0 = (tid & 3) * 16;  // 4 threads per W row, 16 k each
    const float* aptr = &Arow[(size_t)(r0 + arow) * DD + acol];
    const float* wptr = &Wbase[(size_t)(n0b + wn) * wstride + wk0];
    floatx4 acc[2] = {};
    float4 pa0, pa1, pw[4];
    pa0 = *(const float4*)aptr;
    pa1 = *(const float4*)(aptr + 4);
#pragma unroll
    for (int i2 = 0; i2 < 4; ++i2) pw[i2] = *(const float4*)(wptr + i2 * 4);
    for (int c = 0; c < 8; ++c) {
        f16x8 av;
        av[0] = (_Float16)pa0.x; av[1] = (_Float16)pa0.y;
        av[2] = (_Float16)pa0.z; av[3] = (_Float16)pa0.w;
        av[4] = (_Float16)pa1.x; av[5] = (_Float16)pa1.y;
        av[6] = (_Float16)pa1.z; av[7] = (_Float16)pa1.w;
        *(f16x8*)&a_s[arow][acol] = av;
        f16x8 w0, w1;
        w0[0] = (_Float16)pw[0].x; w0[1] = (_Float16)pw[0].y;
        w0[2] = (_Float16)pw[0].z; w0[3] = (_Float16)pw[0].w;
        w0[4] = (_Float16)pw[1].x; w0[5] = (_Float16)pw[1].y;
        w0[6] = (_Float16)pw[1].z; w0[7] = (_Float16)pw[1].w;
        w1[0] = (_Float16)pw[2].x; w1[1] = (_Float16)pw[2].y;
        w1[2] = (_Float16)pw[2].z; w1[3] = (_Float16)pw[2].w;
        w1[4] = (_Float16)pw[3].x; w1[5] = (_Float16)pw[3].y;
        w1[6] = (_Float16)pw[3].z; w1[7] = (_Float16)pw[3].w;
        int kg = wk0 >> 3;
        *(f16x8*)&w_s[((kg + 0) * 64 + wn) * 8] = w0;
        *(f16x8*)&w_s[((kg + 1) * 64 + wn) * 8] = w1;
        __syncthreads();
        if (c < 7) {
            int cb = (c + 1) * 64;
            pa0 = *(const float4*)(aptr + cb);
            pa1 = *(const float4*)(aptr + cb + 4);
#pragma unroll
            for (int i2 = 0; i2 < 4; ++i2)
                pw[i2] = *(const float4*)(wptr + cb + i2 * 4);
        }
#pragma unroll
        for (int kt = 0; kt < 2; ++kt) {
            f16x8 af = *(const f16x8*)&a_s[m0 + r][kt * 32 + q * 8];
#pragma unroll
            for (int nt = 0; nt < 2; ++nt) {
                f16x8 bf = *(const f16x8*)
                    &w_s[((kt * 4 + q) * 64 + n0w + nt * 16 + r) * 8];
                acc[nt] = __builtin_amdgcn_mfma_f32_16x16x32_f16(
                    af, bf, acc[nt], 0, 0, 0);
            }
        }
        __syncthreads();
    }
    const float SC = 2.8853900817779268f;  // 2*log2(e): pre-scale for tanh8z
    if (region == 0) {
#pragma unroll
        for (int nt = 0; nt < 2; ++nt) {
            int n = n0b + n0w + nt * 16 + r;
#pragma unroll
            for (int rr = 0; rr < 4; ++rr)
                imgHf[(size_t)(r0 + m0 + 4 * q + rr) * HH + n] =
                    (_Float16)(acc[nt][rr] * SC);
        }
    } else if (region == 1) {
#pragma unroll
        for (int nt = 0; nt < 2; ++nt) {
            int n = n0b + n0w + nt * 16 + r;
            float bv = b1[n];
#pragma unroll
            for (int rr = 0; rr < 4; ++rr)
                labHf[(size_t)(r0 + m0 + 4 * q + rr) * HH + n] =
                    (_Float16)((acc[nt][rr] + bv) * SC);
        }
    } else {
#pragma unroll
        for (int nt = 0; nt < 2; ++nt) {
            int k = n0b + n0w + nt * 16 + r;
            float bv = conv_b[k];
#pragma unroll
            for (int rr = 0; rr < 4; ++rr) {
                int row = r0 + m0 + 4 * q + rr;
                int b = row >> 9, t = row & 511;
                seg_out[((size_t)b * KK + k) * TT + t] =
                    (acc[nt][rr] + bv) * masks[row];
            }
        }
    }
}

// ---------------- joint v18: v16 + un-sinkable DMA W2 double-buffer --------
// v16 (best, ~36.6us) kept 12 waves/CU but its reg-staged W2 prefetch was
// SUNK by the allocator (VGPR 80 < live-set) -> exposed global latency at
// every chunk head. v18: W2 arrives by global_load_lds DMA (fire-and-forget,
// 0 VGPR, cannot be sunk) into a 2x16KB double buffer, issued one full
// chunk ahead; the A ds_write's ordered vmcnt auto-drains it. A stays
// reg-staged (24 regs; total ~90 < 128 VGPR occupancy step -> stays live).
// Geometry/schedule/compute identical to v16: 768 blocks x 256 thr (4 waves
// x 16 rows), 2 barriers/chunk, rolled loop, 3 blocks/CU (12 waves).
__global__ __launch_bounds__(256) void joint_kernel18(
    const _Float16* __restrict__ imgHf,  // [B*T][H], pre-scaled 2log2e
    const _Float16* __restrict__ labHf,  // [B*U][H], (.+b1) pre-scaled
    const _Float16* __restrict__ W2s,    // swizzled [(h>>3)][k][h&7]
    const float* __restrict__ b2,
    float* __restrict__ out) {           // [B*U*T][K]
    __shared__ __align__(16) _Float16 a_s[64][72];    // 9 KB (+8 pad)
    __shared__ __align__(16) _Float16 w_s[2][8192];   // 2 x 16 KB (DMA dbuf)
    __shared__ __align__(16) _Float16 l_s[64];        // lab chunk (128 B)
    int tid = threadIdx.x, bid = blockIdx.x;
    int lane = tid & 63, wv = tid >> 6;
    int ql = lane >> 4, r = lane & 15;
    int g0 = bid * 64;               // block's first flat (b,u,t) row
    int bu = g0 >> 9;                // single u per block (64 | 512)
    int tbase = ((bu >= UU) ? TT : 0) + (g0 & 511);
    // coalesced A stage: 4 thr/row x 32 B
    int arow = tid >> 2, acol = (tid & 3) * 16;
    const _Float16* ap = imgHf + (size_t)(tbase + arow) * HH + acol;
    const _Float16* lp = labHf + (size_t)bu * HH;
    int m0 = wv * 16;                // wave's rows within block
    floatx4 acc[8] = {};

    // DMA one 16KB W2 chunk into buffer buf: 1024 x 16B units / 256 thr
#define W2DMA(chunk, buf)                                                  \
    {                                                                      \
        const _Float16* ws_ = W2s + (size_t)(chunk) * 8192;                \
        _Pragma("unroll")                                                  \
        for (int j_ = 0; j_ < 4; ++j_) {                                   \
            int u_ = tid + j_ * 256;                                       \
            __builtin_amdgcn_global_load_lds(                              \
                (g_cvoid*)(ws_ + (size_t)u_ * 8),                          \
                (l_void*)((lds_f16*)&w_s[buf][(size_t)u_ * 8]), 16, 0, 0); \
        }                                                                  \
    }

    f16x8 pa0, pa1, plab;
    // prologue: DMA chunk0->buf0; A chunk0 -> regs; DMA chunk1->buf1;
    // ds_write A0 (ordered vmcnt drains A0 loads + DMA0); load A1; barrier
    W2DMA(0, 0);
    pa0 = *(const f16x8*)ap;
    pa1 = *(const f16x8*)(ap + 8);
    if (tid < 8) plab = *(const f16x8*)(lp + tid * 8);
    W2DMA(1, 1);
    *(f16x8*)&a_s[arow][acol] = pa0;
    *(f16x8*)&a_s[arow][acol + 8] = pa1;
    if (tid < 8) *(f16x8*)&l_s[tid * 8] = plab;
    {
        int cb = 64;
        pa0 = *(const f16x8*)(ap + cb);
        pa1 = *(const f16x8*)(ap + cb + 8);
        if (tid < 8) plab = *(const f16x8*)(lp + cb + tid * 8);
    }
    __syncthreads();
#pragma unroll 1
    for (int c = 0; c < 16; ++c) {
        const _Float16* wb = w_s[c & 1];
        // compute chunk c: 2 k-steps x (A-frag + lab from LDS, tanh, 8 MFMA)
#pragma unroll
        for (int kt = 0; kt < 2; ++kt) {
            f16x8 af = *(const f16x8*)&a_s[m0 + r][kt * 32 + ql * 8];
            f16x8 lf = *(const f16x8*)&l_s[kt * 32 + ql * 8];
            f16x8 a = tanh8z(af + lf);
#pragma unroll
            for (int nt = 0; nt < 8; ++nt) {
                f16x8 bf = *(const f16x8*)
                    &wb[((kt * 4 + ql) * 128 + nt * 16 + r) * 8];
                acc[nt] = __builtin_amdgcn_mfma_f32_16x16x32_f16(
                    a, bf, acc[nt], 0, 0, 0);
            }
        }
        __syncthreads();
        if (c < 15) {
            // stage A(c+1) regs -> LDS (ordered vmcnt drains DMA(c+1) too,
            // which has been in flight for the whole of chunk c)
            *(f16x8*)&a_s[arow][acol] = pa0;
            *(f16x8*)&a_s[arow][acol + 8] = pa1;
            if (tid < 8) *(f16x8*)&l_s[tid * 8] = plab;
            if (c < 14) {
                W2DMA(c + 2, c & 1);  // buf just freed by this chunk's reads
                int cb = (c + 2) * 64;
                pa0 = *(const f16x8*)(ap + cb);
                pa1 = *(const f16x8*)(ap + cb + 8);
                if (tid < 8) plab = *(const f16x8*)(lp + cb + tid * 8);
            }
            __syncthreads();
        }
    }
#undef W2DMA
    // epilogue: +b2, in-register log-softmax (wave owns full 128 cols)
    float b2v[8];
#pragma unroll
    for (int nt = 0; nt < 8; ++nt) b2v[nt] = b2[nt * 16 + r];
#pragma unroll
    for (int rr = 0; rr < 4; ++rr) {
        float v[8];
        float mx = -INFINITY;
#pragma unroll
        for (int nt = 0; nt < 8; ++nt) {
            v[nt] = acc[nt][rr] + b2v[nt];
            mx = fmaxf(mx, v[nt]);
        }
        mx = fmaxf(mx, __shfl_xor(mx, 1, 16));
        mx = fmaxf(mx, __shfl_xor(mx, 2, 16));
        mx = fmaxf(mx, __shfl_xor(mx, 4, 16));
        mx = fmaxf(mx, __shfl_xor(mx, 8, 16));
        float s = 0.f;
#pragma unroll
        for (int nt = 0; nt < 8; ++nt) s += __expf(v[nt] - mx);
        s += __shfl_xor(s, 1, 16);
        s += __shfl_xor(s, 2, 16);
        s += __shfl_xor(s, 4, 16);
        s += __shfl_xor(s, 8, 16);
        float lse = mx + __logf(s);
        float* orow = out + (size_t)(g0 + m0 + 4 * ql + rr) * KK;
#pragma unroll
        for (int nt = 0; nt < 8; ++nt)
            orow[nt * 16 + r] = v[nt] - lse;
    }
}

extern "C" void kernel_launch(void* const* d_in, const int* in_sizes, int n_in,
                              void* d_out, int out_size, void* d_ws, size_t ws_size,
                              hipStream_t stream) {
    const float* img    = (const float*)d_in[0];
    const float* labf   = (const float*)d_in[1];
    const float* masks  = (const float*)d_in[2];
    const float* W1     = (const float*)d_in[3];
    const float* b1     = (const float*)d_in[4];
    const float* W2     = (const float*)d_in[5];
    const float* b2     = (const float*)d_in[6];
    const float* conv_w = (const float*)d_in[7];
    const float* conv_b = (const float*)d_in[8];
    float* out = (float*)d_out;

    _Float16* base  = (_Float16*)d_ws;
    _Float16* imgHf = base;                    // [1024][1024]
    _Float16* labHf = imgHf + 1024 * 1024;     // [96][1024]
    _Float16* W2s   = labHf + 96 * 1024;       // [H/8][K][8] = 131072

    mid_kernel5<<<640, 256, 0, stream>>>(img, labf, W1, W2, conv_w,
                                         b1, conv_b, masks,
                                         imgHf, labHf, W2s, out);
    joint_kernel18<<<768, 256, 0, stream>>>(imgHf, labHf, W2s, b2,
                                            out + (size_t)BB * KK * TT);
}

// Round 15
// 118.808 us; speedup vs baseline: 1.0515x; 1.0351x over previous
//
#include <hip/hip_runtime.h>
#include <math.h>

#define BB 2
#define TT 512
#define UU 48
#define DD 512
#define HH 1024
#define KK 128

typedef _Float16 f16x8 __attribute__((ext_vector_type(8)));
typedef __fp16 fp16x2_t __attribute__((ext_vector_type(2)));
typedef float floatx4 __attribute__((ext_vector_type(4)));

// tanh from pre-scaled input z = 2*log2(e)*x (stored f16 by mid):
// tanh(x) = 1 - 2/(2^z + 1). 2 trans + ~5 VALU per 2 elems, +-inf safe.
__device__ __forceinline__ f16x8 tanh8z(f16x8 z) {
    f16x8 o;
#pragma unroll
    for (int i = 0; i < 8; i += 2) {
        float e0 = __builtin_amdgcn_exp2f((float)z[i]);
        float e1 = __builtin_amdgcn_exp2f((float)z[i + 1]);
        float r0 = __builtin_amdgcn_rcpf(e0 + 1.0f);
        float r1 = __builtin_amdgcn_rcpf(e1 + 1.0f);
        fp16x2_t p = __builtin_amdgcn_cvt_pkrtz(fmaf(-2.0f, r0, 1.0f),
                                                fmaf(-2.0f, r1, 1.0f));
        o[i] = (_Float16)p[0];
        o[i + 1] = (_Float16)p[1];
    }
    return o;
}

// ---------------- mid v5: unchanged --------------------------------------
__global__ __launch_bounds__(256) void mid_kernel5(
    const float* __restrict__ img, const float* __restrict__ labf,
    const float* __restrict__ W1, const float* __restrict__ W2,
    const float* __restrict__ conv_w,
    const float* __restrict__ b1, const float* __restrict__ conv_b,
    const float* __restrict__ masks,
    _Float16* __restrict__ imgHf, _Float16* __restrict__ labHf,
    _Float16* __restrict__ W2s, float* __restrict__ seg_out) {
    int bid = blockIdx.x, tid = threadIdx.x;
    if (bid >= 624) {  // W2 swizzle: W2s[(h>>3)*1024 + k*8 + (h&7)] = W2[k][h]
        int base = (bid - 624) * 256 + tid;
#pragma unroll
        for (int i = 0; i < 32; ++i) {
            int o = base + i * 4096;
            int hg = o >> 10, kk2 = (o >> 3) & 127, hl = o & 7;
            W2s[o] = (_Float16)W2[(size_t)kk2 * HH + hg * 8 + hl];
        }
        return;
    }
    __shared__ __align__(16) _Float16 a_s[32][72];
    __shared__ __align__(16) _Float16 w_s[4096];  // [8 kgroups][64 n][8]
    const float* Arow;
    const float* Wbase;
    int r0, n0b, wstride, region;
    if (bid < 512) {
        region = 0; Arow = img; Wbase = W1 + 512; wstride = 2 * DD;
        int xcd = bid & 7, j = bid >> 3;
        r0 = (j & 31) * 32; n0b = (xcd * 2 + (j >> 5)) * 64;
    } else if (bid < 560) {
        region = 1; Arow = labf; Wbase = W1; wstride = 2 * DD;
        int i = bid - 512; r0 = (i % 3) * 32; n0b = (i / 3) * 64;
    } else {
        region = 2; Arow = img; Wbase = conv_w; wstride = DD;
        int i = bid - 560; r0 = (i >> 1) * 32; n0b = (i & 1) * 64;
    }
    int lane = tid & 63, wv = tid >> 6;
    int m0 = (wv & 1) * 16, n0w = (wv >> 1) * 32;
    int q = lane >> 4, r = lane & 15;
    int arow = tid >> 3, acol = (tid & 7) * 8;
    int wn = tid >> 2, wk0 = (tid & 3) * 16;  // 4 threads per W row, 16 k each
    const float* aptr = &Arow[(size_t)(r0 + arow) * DD + acol];
    const float* wptr = &Wbase[(size_t)(n0b + wn) * wstride + wk0];
    floatx4 acc[2] = {};
    float4 pa0, pa1, pw[4];
    pa0 = *(const float4*)aptr;
    pa1 = *(const float4*)(aptr + 4);
#pragma unroll
    for (int i2 = 0; i2 < 4; ++i2) pw[i2] = *(const float4*)(wptr + i2 * 4);
    for (int c = 0; c < 8; ++c) {
        f16x8 av;
        av[0] = (_Float16)pa0.x; av[1] = (_Float16)pa0.y;
        av[2] = (_Float16)pa0.z; av[3] = (_Float16)pa0.w;
        av[4] = (_Float16)pa1.x; av[5] = (_Float16)pa1.y;
        av[6] = (_Float16)pa1.z; av[7] = (_Float16)pa1.w;
        *(f16x8*)&a_s[arow][acol] = av;
        f16x8 w0, w1;
        w0[0] = (_Float16)pw[0].x; w0[1] = (_Float16)pw[0].y;
        w0[2] = (_Float16)pw[0].z; w0[3] = (_Float16)pw[0].w;
        w0[4] = (_Float16)pw[1].x; w0[5] = (_Float16)pw[1].y;
        w0[6] = (_Float16)pw[1].z; w0[7] = (_Float16)pw[1].w;
        w1[0] = (_Float16)pw[2].x; w1[1] = (_Float16)pw[2].y;
        w1[2] = (_Float16)pw[2].z; w1[3] = (_Float16)pw[2].w;
        w1[4] = (_Float16)pw[3].x; w1[5] = (_Float16)pw[3].y;
        w1[6] = (_Float16)pw[3].z; w1[7] = (_Float16)pw[3].w;
        int kg = wk0 >> 3;
        *(f16x8*)&w_s[((kg + 0) * 64 + wn) * 8] = w0;
        *(f16x8*)&w_s[((kg + 1) * 64 + wn) * 8] = w1;
        __syncthreads();
        if (c < 7) {
            int cb = (c + 1) * 64;
            pa0 = *(const float4*)(aptr + cb);
            pa1 = *(const float4*)(aptr + cb + 4);
#pragma unroll
            for (int i2 = 0; i2 < 4; ++i2)
                pw[i2] = *(const float4*)(wptr + cb + i2 * 4);
        }
#pragma unroll
        for (int kt = 0; kt < 2; ++kt) {
            f16x8 af = *(const f16x8*)&a_s[m0 + r][kt * 32 + q * 8];
#pragma unroll
            for (int nt = 0; nt < 2; ++nt) {
                f16x8 bf = *(const f16x8*)
                    &w_s[((kt * 4 + q) * 64 + n0w + nt * 16 + r) * 8];
                acc[nt] = __builtin_amdgcn_mfma_f32_16x16x32_f16(
                    af, bf, acc[nt], 0, 0, 0);
            }
        }
        __syncthreads();
    }
    const float SC = 2.8853900817779268f;  // 2*log2(e): pre-scale for tanh8z
    if (region == 0) {
#pragma unroll
        for (int nt = 0; nt < 2; ++nt) {
            int n = n0b + n0w + nt * 16 + r;
#pragma unroll
            for (int rr = 0; rr < 4; ++rr)
                imgHf[(size_t)(r0 + m0 + 4 * q + rr) * HH + n] =
                    (_Float16)(acc[nt][rr] * SC);
        }
    } else if (region == 1) {
#pragma unroll
        for (int nt = 0; nt < 2; ++nt) {
            int n = n0b + n0w + nt * 16 + r;
            float bv = b1[n];
#pragma unroll
            for (int rr = 0; rr < 4; ++rr)
                labHf[(size_t)(r0 + m0 + 4 * q + rr) * HH + n] =
                    (_Float16)((acc[nt][rr] + bv) * SC);
        }
    } else {
#pragma unroll
        for (int nt = 0; nt < 2; ++nt) {
            int k = n0b + n0w + nt * 16 + r;
            float bv = conv_b[k];
#pragma unroll
            for (int rr = 0; rr < 4; ++rr) {
                int row = r0 + m0 + 4 * q + rr;
                int b = row >> 9, t = row & 511;
                seg_out[((size_t)b * KK + k) * TT + t] =
                    (acc[nt][rr] + bv) * masks[row];
            }
        }
    }
}

// ---------------- joint v19: split-H wave pairs (bf-sharing AT 12 waves/CU)
// v16 is LDS-read-bound; bf reads dominate (each wave reads the full 16KB
// W2 chunk for 16 rows). v17's m-sharing halved reads but also halved
// occupancy (FAIL). v19 decouples them: wave = (row-group rg, H-half hh) =
// 32 rows x 512 h. Per time step t=0..7, wave computes chunk hh*8+t. Waves
// stay 3072 (12/CU); each bf feeds 2 MFMAs; per-wave LDS reads 320->176KB.
// Schedule identical to v16 (reg-staged coalesced -> LDS, 2 barriers/step).
// Epilogue: wave pairs exchange one acc-half via w_s (+1 barrier), then the
// same wave-local softmax (hh0 -> rows 0-15 of its group, hh1 -> rows 16-31).
__global__ __launch_bounds__(256) void joint_kernel19(
    const _Float16* __restrict__ imgHf,  // [B*T][H], pre-scaled 2log2e
    const _Float16* __restrict__ labHf,  // [B*U][H], (.+b1) pre-scaled
    const _Float16* __restrict__ W2s,    // swizzled [(h>>3)][k][h&7]
    const float* __restrict__ b2,
    float* __restrict__ out) {           // [B*U*T][K]
    __shared__ __align__(16) _Float16 a_s[2][64][72];  // 18 KB (+8 pad)
    __shared__ __align__(16) _Float16 w_s[2][8192];    // 32 KB (2 chunks)
    __shared__ __align__(16) _Float16 l_s[2][64];      // 256 B lab chunks
    int tid = threadIdx.x, bid = blockIdx.x;
    int lane = tid & 63, wv = tid >> 6;
    int rg = wv >> 1, hh = wv & 1;   // row-group 0/1, H-half 0/1
    int ql = lane >> 4, r = lane & 15;
    int g0 = bid * 64;               // block's first flat (b,u,t) row
    int bu = g0 >> 9;                // single u per block (64 | 512)
    int tbase = ((bu >= UU) ? TT : 0) + (g0 & 511);
    // coalesced A stage: 4 thr/row x 16 f16; both halves per thread
    int arow = tid >> 2, acol = (tid & 3) * 16;
    const _Float16* ap0 = imgHf + (size_t)(tbase + arow) * HH + acol;        // h<512
    const _Float16* ap1 = ap0 + 512;                                         // h>=512
    const _Float16* lp = labHf + (size_t)bu * HH;
    int m0r = rg * 32;               // wave pair's row base within block
    floatx4 acc0[8] = {}, acc1[8] = {};
    f16x8 pa00, pa01, pa10, pa11;    // A stage regs [half][seg]
    f16x8 pw0[4], pw1[4], plab;
    // prologue: t=0 regs
    pa00 = *(const f16x8*)ap0;  pa01 = *(const f16x8*)(ap0 + 8);
    pa10 = *(const f16x8*)ap1;  pa11 = *(const f16x8*)(ap1 + 8);
#pragma unroll
    for (int j = 0; j < 4; ++j) {
        pw0[j] = *(const f16x8*)(W2s + (size_t)0 * 8192 + tid * 8 + j * 2048);
        pw1[j] = *(const f16x8*)(W2s + (size_t)8 * 8192 + tid * 8 + j * 2048);
    }
    if (tid < 16)
        plab = *(const f16x8*)(lp + (tid >> 3) * 512 + (tid & 7) * 8);
#pragma unroll 1
    for (int t = 0; t < 8; ++t) {
        // store staged regs -> LDS (both halves)
        *(f16x8*)&a_s[0][arow][acol] = pa00;
        *(f16x8*)&a_s[0][arow][acol + 8] = pa01;
        *(f16x8*)&a_s[1][arow][acol] = pa10;
        *(f16x8*)&a_s[1][arow][acol + 8] = pa11;
#pragma unroll
        for (int j = 0; j < 4; ++j) {
            *(f16x8*)&w_s[0][tid * 8 + j * 2048] = pw0[j];
            *(f16x8*)&w_s[1][tid * 8 + j * 2048] = pw1[j];
        }
        if (tid < 16) *(f16x8*)&l_s[tid >> 3][(tid & 7) * 8] = plab;
        __syncthreads();
        // issue next step's loads; they drain during tanh+MFMA below
        if (t < 7) {
            int cb = (t + 1) * 64;
            pa00 = *(const f16x8*)(ap0 + cb);
            pa01 = *(const f16x8*)(ap0 + cb + 8);
            pa10 = *(const f16x8*)(ap1 + cb);
            pa11 = *(const f16x8*)(ap1 + cb + 8);
#pragma unroll
            for (int j = 0; j < 4; ++j) {
                pw0[j] = *(const f16x8*)(W2s + (size_t)(t + 1) * 8192 +
                                         tid * 8 + j * 2048);
                pw1[j] = *(const f16x8*)(W2s + (size_t)(t + 9) * 8192 +
                                         tid * 8 + j * 2048);
            }
            if (tid < 16)
                plab = *(const f16x8*)(lp + (tid >> 3) * 512 + cb +
                                       (tid & 7) * 8);
        }
        // compute: wave (rg,hh) does its half's chunk; bf feeds 2 m-tiles
#pragma unroll
        for (int kt = 0; kt < 2; ++kt) {
            f16x8 lf = *(const f16x8*)&l_s[hh][kt * 32 + ql * 8];
            f16x8 af0 = *(const f16x8*)&a_s[hh][m0r + r][kt * 32 + ql * 8];
            f16x8 af1 =
                *(const f16x8*)&a_s[hh][m0r + 16 + r][kt * 32 + ql * 8];
            f16x8 a0 = tanh8z(af0 + lf);
            f16x8 a1 = tanh8z(af1 + lf);
#pragma unroll
            for (int nt = 0; nt < 8; ++nt) {
                f16x8 bf = *(const f16x8*)
                    &w_s[hh][((kt * 4 + ql) * 128 + nt * 16 + r) * 8];
                acc0[nt] = __builtin_amdgcn_mfma_f32_16x16x32_f16(
                    a0, bf, acc0[nt], 0, 0, 0);
                acc1[nt] = __builtin_amdgcn_mfma_f32_16x16x32_f16(
                    a1, bf, acc1[nt], 0, 0, 0);
            }
        }
        __syncthreads();
    }
    // cross-half reduce via w_s (32KB = 4 waves x 8KB exactly):
    // hh0 gives acc1 (keeps rows 0-15); hh1 gives acc0 (keeps rows 16-31)
    {
        float* red = (float*)w_s;
        float* myout = red + (size_t)wv * 2048;
#pragma unroll
        for (int nt = 0; nt < 8; ++nt)
            *(floatx4*)&myout[nt * 256 + lane * 4] = hh ? acc0[nt] : acc1[nt];
        __syncthreads();
        float* other = red + (size_t)(wv ^ 1) * 2048;
#pragma unroll
        for (int nt = 0; nt < 8; ++nt) {
            floatx4 v = *(const floatx4*)&other[nt * 256 + lane * 4];
            if (hh) acc1[nt] += v; else acc0[nt] += v;
        }
    }
    // epilogue: +b2, wave-local log-softmax on the kept acc (16 rows)
    float b2v[8];
#pragma unroll
    for (int nt = 0; nt < 8; ++nt) b2v[nt] = b2[nt * 16 + r];
#pragma unroll
    for (int rr = 0; rr < 4; ++rr) {
        float v[8];
        float mx = -INFINITY;
#pragma unroll
        for (int nt = 0; nt < 8; ++nt) {
            v[nt] = (hh ? acc1[nt][rr] : acc0[nt][rr]) + b2v[nt];
            mx = fmaxf(mx, v[nt]);
        }
        mx = fmaxf(mx, __shfl_xor(mx, 1, 16));
        mx = fmaxf(mx, __shfl_xor(mx, 2, 16));
        mx = fmaxf(mx, __shfl_xor(mx, 4, 16));
        mx = fmaxf(mx, __shfl_xor(mx, 8, 16));
        float s = 0.f;
#pragma unroll
        for (int nt = 0; nt < 8; ++nt) s += __expf(v[nt] - mx);
        s += __shfl_xor(s, 1, 16);
        s += __shfl_xor(s, 2, 16);
        s += __shfl_xor(s, 4, 16);
        s += __shfl_xor(s, 8, 16);
        float lse = mx + __logf(s);
        float* orow =
            out + (size_t)(g0 + m0r + hh * 16 + 4 * ql + rr) * KK;
#pragma unroll
        for (int nt = 0; nt < 8; ++nt)
            orow[nt * 16 + r] = v[nt] - lse;
    }
}

extern "C" void kernel_launch(void* const* d_in, const int* in_sizes, int n_in,
                              void* d_out, int out_size, void* d_ws, size_t ws_size,
                              hipStream_t stream) {
    const float* img    = (const float*)d_in[0];
    const float* labf   = (const float*)d_in[1];
    const float* masks  = (const float*)d_in[2];
    const float* W1     = (const float*)d_in[3];
    const float* b1     = (const float*)d_in[4];
    const float* W2     = (const float*)d_in[5];
    const float* b2     = (const float*)d_in[6];
    const float* conv_w = (const float*)d_in[7];
    const float* conv_b = (const float*)d_in[8];
    float* out = (float*)d_out;

    _Float16* base  = (_Float16*)d_ws;
    _Float16* imgHf = base;                    // [1024][1024]
    _Float16* labHf = imgHf + 1024 * 1024;     // [96][1024]
    _Float16* W2s   = labHf + 96 * 1024;       // [H/8][K][8] = 131072

    mid_kernel5<<<640, 256, 0, stream>>>(img, labf, W1, W2, conv_w,
                                         b1, conv_b, masks,
                                         imgHf, labHf, W2s, out);
    joint_kernel19<<<768, 256, 0, stream>>>(imgHf, labHf, W2s, b2,
                                            out + (size_t)BB * KK * TT);
}